// Round 1
// baseline (417.292 us; speedup 1.0000x reference)
//
#include <hip/hip_runtime.h>

#define NLAT 721
#define NLON 1440
#define NPIX (NLAT * NLON)   // 1,038,240 (divisible by 4)
#define BATCH 8
#define NCLS 16
#define IGNORE_IDX (-100)

// Main pass: per-pixel argmax over 16 classes + weighted match/unmatch sums.
// Grid: (ceil(NPIX/4/256), BATCH). Each thread handles 4 consecutive pixels.
__global__ __launch_bounds__(256) void metric_main_kernel(
    const float* __restrict__ pred,   // [B, C, NPIX]
    const int*   __restrict__ truth,  // [B, NPIX] (int32 per harness contract)
    const float* __restrict__ qw,     // [NPIX]
    double*      __restrict__ acc)    // [4]: tp, fp, fn, qwsum
{
    const int i4 = blockIdx.x * 256 + threadIdx.x;
    const int b  = blockIdx.y;

    float tp = 0.f, fp = 0.f, fn = 0.f, qs = 0.f;

    if (i4 < NPIX / 4) {
        const int i = i4 * 4;
        const float* pb = pred + (size_t)b * NCLS * NPIX + i;

        // argmax over class dim; strict '>' keeps the FIRST max (jnp.argmax).
        float4 best = *reinterpret_cast<const float4*>(pb);
        int bx = 0, by = 0, bz = 0, bw = 0;
        #pragma unroll
        for (int c = 1; c < NCLS; ++c) {
            float4 v = *reinterpret_cast<const float4*>(pb + (size_t)c * NPIX);
            if (v.x > best.x) { best.x = v.x; bx = c; }
            if (v.y > best.y) { best.y = v.y; by = c; }
            if (v.z > best.z) { best.z = v.z; bz = c; }
            if (v.w > best.w) { best.w = v.w; bw = c; }
        }

        const int4   t = *reinterpret_cast<const int4*>(truth + (size_t)b * NPIX + i);
        const float4 w = *reinterpret_cast<const float4*>(qw + i);

        const int   oc[4] = {bx, by, bz, bw};
        const int   tt[4] = {t.x, t.y, t.z, t.w};
        const float ww[4] = {w.x, w.y, w.z, w.w};

        #pragma unroll
        for (int e = 0; e < 4; ++e) {
            const bool ign = (tt[e] == IGNORE_IDX);
            const int  tv  = ign ? -1 : tt[e];
            const int  ov  = ign ? -1 : oc[e];
            const bool matched = (tv == ov);
            const bool vt = (tv >= 0) && (tv < NCLS);
            const bool vo = (ov >= 0) && (ov < NCLS);
            const float wv = ww[e];
            if (matched  && vt) tp += wv;
            if (!matched && vt) fn += wv;
            if (!matched && vo) fp += wv;
        }
        if (b == 0) qs = ww[0] + ww[1] + ww[2] + ww[3];
    }

    // Wave64 butterfly reduce (all threads participate, OOB threads carry 0).
    #pragma unroll
    for (int off = 32; off > 0; off >>= 1) {
        tp += __shfl_down(tp, off);
        fp += __shfl_down(fp, off);
        fn += __shfl_down(fn, off);
        qs += __shfl_down(qs, off);
    }

    __shared__ float s[4][4];
    const int wid  = threadIdx.x >> 6;
    const int lane = threadIdx.x & 63;
    if (lane == 0) { s[wid][0] = tp; s[wid][1] = fp; s[wid][2] = fn; s[wid][3] = qs; }
    __syncthreads();

    if (threadIdx.x == 0) {
        float a0 = 0.f, a1 = 0.f, a2 = 0.f, a3 = 0.f;
        #pragma unroll
        for (int k = 0; k < 4; ++k) {
            a0 += s[k][0]; a1 += s[k][1]; a2 += s[k][2]; a3 += s[k][3];
        }
        atomicAdd(&acc[0], (double)a0);
        atomicAdd(&acc[1], (double)a1);
        atomicAdd(&acc[2], (double)a2);
        atomicAdd(&acc[3], (double)a3);
    }
}

__global__ void metric_final_kernel(const double* __restrict__ acc,
                                    float* __restrict__ out)
{
    if (blockIdx.x == 0 && threadIdx.x == 0) {
        const double inv = 1.0 / (double)(BATCH * NCLS);
        const double tp = acc[0] * inv;
        const double fp = acc[1] * inv;
        const double fn = acc[2] * inv;
        const double tn = acc[3] - tp - fp - fn;  // mean(tn) = sum(qw) - means
        out[0] = (float)tp;
        out[1] = (float)fp;
        out[2] = (float)fn;
        out[3] = (float)tn;
    }
}

extern "C" void kernel_launch(void* const* d_in, const int* in_sizes, int n_in,
                              void* d_out, int out_size, void* d_ws, size_t ws_size,
                              hipStream_t stream) {
    const float* pred  = (const float*)d_in[0];
    const int*   truth = (const int*)d_in[1];
    const float* qw    = (const float*)d_in[2];
    float*  out = (float*)d_out;
    double* acc = (double*)d_ws;

    // Zero the 4 double accumulators every launch (harness does not re-poison).
    hipMemsetAsync(acc, 0, 4 * sizeof(double), stream);

    dim3 grid((NPIX / 4 + 255) / 256, BATCH);
    metric_main_kernel<<<grid, 256, 0, stream>>>(pred, truth, qw, acc);
    metric_final_kernel<<<1, 1, 0, stream>>>(acc, out);
}

// Round 2
// 416.284 us; speedup vs baseline: 1.0024x; 1.0024x over previous
//
#include <hip/hip_runtime.h>

#define NLAT 721
#define NLON 1440
#define NPIX (NLAT * NLON)   // 1,038,240 (divisible by 4)
#define BATCH 8
#define NCLS 16
#define IGNORE_IDX (-100)

// Main pass: per-pixel argmax over 16 classes + weighted match/unmatch sums.
// Grid: (NPIX/4/256 rounded up, BATCH). Each thread handles 4 consecutive
// pixels. All 16 class loads are issued as an independent burst (ILP=16) so
// the wave has 16 outstanding global_load_dwordx4 — the R1 kernel serialized
// them (VGPR=32) and was latency-bound at 720 GB/s.
__global__ __launch_bounds__(256) void metric_main_kernel(
    const float* __restrict__ pred,   // [B, C, NPIX]
    const int*   __restrict__ truth,  // [B, NPIX] (int32 per harness contract)
    const float* __restrict__ qw,     // [NPIX]
    double*      __restrict__ acc)    // [4]: tp, fp, fn, qwsum
{
    const int i4 = blockIdx.x * 256 + threadIdx.x;
    const int b  = blockIdx.y;

    float tp = 0.f, fp = 0.f, fn = 0.f, qs = 0.f;

    if (i4 < NPIX / 4) {
        const int i = i4 * 4;
        const float* pb = pred + (size_t)b * NCLS * NPIX + i;

        // Burst-load all 16 class rows FIRST (independent loads, ILP=16).
        float4 v[NCLS];
        #pragma unroll
        for (int c = 0; c < NCLS; ++c) {
            v[c] = *reinterpret_cast<const float4*>(pb + (size_t)c * NPIX);
        }
        const int4   t = *reinterpret_cast<const int4*>(truth + (size_t)b * NPIX + i);
        const float4 w = *reinterpret_cast<const float4*>(qw + i);

        // Branchless argmax; strict '>' keeps the FIRST max (jnp.argmax tie rule).
        float4 best = v[0];
        int bx = 0, by = 0, bz = 0, bw = 0;
        #pragma unroll
        for (int c = 1; c < NCLS; ++c) {
            bx = (v[c].x > best.x) ? c : bx;  best.x = fmaxf(best.x, v[c].x);
            by = (v[c].y > best.y) ? c : by;  best.y = fmaxf(best.y, v[c].y);
            bz = (v[c].z > best.z) ? c : bz;  best.z = fmaxf(best.z, v[c].z);
            bw = (v[c].w > best.w) ? c : bw;  best.w = fmaxf(best.w, v[c].w);
        }

        const int   oc[4] = {bx, by, bz, bw};
        const int   tt[4] = {t.x, t.y, t.z, t.w};
        const float ww[4] = {w.x, w.y, w.z, w.w};

        #pragma unroll
        for (int e = 0; e < 4; ++e) {
            const bool ign = (tt[e] == IGNORE_IDX);
            const int  tv  = ign ? -1 : tt[e];
            const int  ov  = ign ? -1 : oc[e];
            const bool matched = (tv == ov);
            const bool vt = (tv >= 0) && (tv < NCLS);
            const bool vo = (ov >= 0) && (ov < NCLS);
            const float wv = ww[e];
            tp += (matched  && vt) ? wv : 0.f;
            fn += (!matched && vt) ? wv : 0.f;
            fp += (!matched && vo) ? wv : 0.f;
        }
        if (b == 0) qs = ww[0] + ww[1] + ww[2] + ww[3];
    }

    // Wave64 reduce (all threads participate, OOB threads carry 0).
    #pragma unroll
    for (int off = 32; off > 0; off >>= 1) {
        tp += __shfl_down(tp, off);
        fp += __shfl_down(fp, off);
        fn += __shfl_down(fn, off);
        qs += __shfl_down(qs, off);
    }

    __shared__ float s[4][4];
    const int wid  = threadIdx.x >> 6;
    const int lane = threadIdx.x & 63;
    if (lane == 0) { s[wid][0] = tp; s[wid][1] = fp; s[wid][2] = fn; s[wid][3] = qs; }
    __syncthreads();

    if (threadIdx.x == 0) {
        float a0 = 0.f, a1 = 0.f, a2 = 0.f, a3 = 0.f;
        #pragma unroll
        for (int k = 0; k < 4; ++k) {
            a0 += s[k][0]; a1 += s[k][1]; a2 += s[k][2]; a3 += s[k][3];
        }
        atomicAdd(&acc[0], (double)a0);
        atomicAdd(&acc[1], (double)a1);
        atomicAdd(&acc[2], (double)a2);
        atomicAdd(&acc[3], (double)a3);
    }
}

__global__ void metric_final_kernel(const double* __restrict__ acc,
                                    float* __restrict__ out)
{
    if (blockIdx.x == 0 && threadIdx.x == 0) {
        const double inv = 1.0 / (double)(BATCH * NCLS);
        const double tp = acc[0] * inv;
        const double fp = acc[1] * inv;
        const double fn = acc[2] * inv;
        const double tn = acc[3] - tp - fp - fn;  // mean(tn) = sum(qw) - means
        out[0] = (float)tp;
        out[1] = (float)fp;
        out[2] = (float)fn;
        out[3] = (float)tn;
    }
}

extern "C" void kernel_launch(void* const* d_in, const int* in_sizes, int n_in,
                              void* d_out, int out_size, void* d_ws, size_t ws_size,
                              hipStream_t stream) {
    const float* pred  = (const float*)d_in[0];
    const int*   truth = (const int*)d_in[1];
    const float* qw    = (const float*)d_in[2];
    float*  out = (float*)d_out;
    double* acc = (double*)d_ws;

    // Zero the 4 double accumulators every launch (harness does not re-poison).
    hipMemsetAsync(acc, 0, 4 * sizeof(double), stream);

    dim3 grid((NPIX / 4 + 255) / 256, BATCH);
    metric_main_kernel<<<grid, 256, 0, stream>>>(pred, truth, qw, acc);
    metric_final_kernel<<<1, 1, 0, stream>>>(acc, out);
}

// Round 3
// 106.998 us; speedup vs baseline: 3.9000x; 3.8906x over previous
//
#include <hip/hip_runtime.h>

#define NLAT 721
#define NLON 1440
#define NPIX (NLAT * NLON)   // 1,038,240 (divisible by 4)
#define NQ   (NPIX / 4)      // 259,560 quads per batch
#define BATCH 8
#define NCLS 16
#define IGNORE_IDX (-100)
#define QBLOCKS 256          // x-blocks per batch -> 2048 blocks total

typedef float vf4 __attribute__((ext_vector_type(4)));

// Main pass: per-pixel argmax over 16 classes + weighted match/unmatch sums.
// Grid: (QBLOCKS, BATCH), 256 threads. Each thread grid-strides over quads
// (~4 iters). No global atomics: each block writes a float4 partial to ws.
__global__ __launch_bounds__(256) void metric_main_kernel(
    const float* __restrict__ pred,     // [B, C, NPIX]
    const int*   __restrict__ truth,    // [B, NPIX]
    const float* __restrict__ qw,       // [NPIX]
    float4*      __restrict__ partials) // [BATCH*QBLOCKS] {tp,fp,fn,qs}
{
    const int b = blockIdx.y;
    const float* pb = pred  + (size_t)b * NCLS * NPIX;
    const int*   tb = truth + (size_t)b * NPIX;

    float tp = 0.f, fp = 0.f, fn = 0.f, qs = 0.f;

    for (int q = blockIdx.x * 256 + threadIdx.x; q < NQ; q += QBLOCKS * 256) {
        const int i = q * 4;

        // Burst: all 16 class loads issued before any use. The asm pins all
        // 16 float4s live at one point so the compiler cannot re-serialize
        // the loads to save registers (R2 failure mode: VGPR=36, 417us).
        vf4 v[NCLS];
        #pragma unroll
        for (int c = 0; c < NCLS; ++c)
            v[c] = *reinterpret_cast<const vf4*>(pb + (size_t)c * NPIX + i);
        asm volatile("" : "+v"(v[0]), "+v"(v[1]), "+v"(v[2]), "+v"(v[3]),
                          "+v"(v[4]), "+v"(v[5]), "+v"(v[6]), "+v"(v[7]),
                          "+v"(v[8]), "+v"(v[9]), "+v"(v[10]), "+v"(v[11]),
                          "+v"(v[12]), "+v"(v[13]), "+v"(v[14]), "+v"(v[15]));

        const int4   t = *reinterpret_cast<const int4*>(tb + i);
        const float4 w = *reinterpret_cast<const float4*>(qw + i);

        // Branchless argmax; strict '>' keeps FIRST max (jnp.argmax tie rule).
        vf4 best = v[0];
        int bx = 0, by = 0, bz = 0, bw = 0;
        #pragma unroll
        for (int c = 1; c < NCLS; ++c) {
            bx = (v[c].x > best.x) ? c : bx;  best.x = fmaxf(best.x, v[c].x);
            by = (v[c].y > best.y) ? c : by;  best.y = fmaxf(best.y, v[c].y);
            bz = (v[c].z > best.z) ? c : bz;  best.z = fmaxf(best.z, v[c].z);
            bw = (v[c].w > best.w) ? c : bw;  best.w = fmaxf(best.w, v[c].w);
        }

        const int   oc[4] = {bx, by, bz, bw};
        const int   tt[4] = {t.x, t.y, t.z, t.w};
        const float ww[4] = {w.x, w.y, w.z, w.w};

        #pragma unroll
        for (int e = 0; e < 4; ++e) {
            const bool ign = (tt[e] == IGNORE_IDX);
            const int  tv  = ign ? -1 : tt[e];
            const int  ov  = ign ? -1 : oc[e];
            const bool matched = (tv == ov);
            const bool vt = (tv >= 0) && (tv < NCLS);
            const bool vo = (ov >= 0) && (ov < NCLS);
            const float wv = ww[e];
            tp += (matched  && vt) ? wv : 0.f;
            fn += (!matched && vt) ? wv : 0.f;
            fp += (!matched && vo) ? wv : 0.f;
        }
        if (b == 0) qs += ww[0] + ww[1] + ww[2] + ww[3];
    }

    // Wave64 reduce.
    #pragma unroll
    for (int off = 32; off > 0; off >>= 1) {
        tp += __shfl_down(tp, off);
        fp += __shfl_down(fp, off);
        fn += __shfl_down(fn, off);
        qs += __shfl_down(qs, off);
    }

    __shared__ float s[4][4];
    const int wid  = threadIdx.x >> 6;
    const int lane = threadIdx.x & 63;
    if (lane == 0) { s[wid][0] = tp; s[wid][1] = fp; s[wid][2] = fn; s[wid][3] = qs; }
    __syncthreads();

    if (threadIdx.x == 0) {
        float4 p = make_float4(0.f, 0.f, 0.f, 0.f);
        #pragma unroll
        for (int k = 0; k < 4; ++k) {
            p.x += s[k][0]; p.y += s[k][1]; p.z += s[k][2]; p.w += s[k][3];
        }
        partials[blockIdx.y * QBLOCKS + blockIdx.x] = p;  // plain store, no atomic
    }
}

// Reduce 2048 float4 partials -> 4 outputs (double accumulation at the end).
__global__ __launch_bounds__(256) void metric_final_kernel(
    const float4* __restrict__ partials, float* __restrict__ out)
{
    float a0 = 0.f, a1 = 0.f, a2 = 0.f, a3 = 0.f;
    for (int k = threadIdx.x; k < BATCH * QBLOCKS; k += 256) {
        const float4 p = partials[k];
        a0 += p.x; a1 += p.y; a2 += p.z; a3 += p.w;
    }
    #pragma unroll
    for (int off = 32; off > 0; off >>= 1) {
        a0 += __shfl_down(a0, off);
        a1 += __shfl_down(a1, off);
        a2 += __shfl_down(a2, off);
        a3 += __shfl_down(a3, off);
    }
    __shared__ float s[4][4];
    const int wid  = threadIdx.x >> 6;
    const int lane = threadIdx.x & 63;
    if (lane == 0) { s[wid][0] = a0; s[wid][1] = a1; s[wid][2] = a2; s[wid][3] = a3; }
    __syncthreads();

    if (threadIdx.x == 0) {
        double tp = 0.0, fp = 0.0, fn = 0.0, qs = 0.0;
        #pragma unroll
        for (int k = 0; k < 4; ++k) {
            tp += s[k][0]; fp += s[k][1]; fn += s[k][2]; qs += s[k][3];
        }
        const double inv = 1.0 / (double)(BATCH * NCLS);
        tp *= inv; fp *= inv; fn *= inv;
        out[0] = (float)tp;
        out[1] = (float)fp;
        out[2] = (float)fn;
        out[3] = (float)(qs - tp - fp - fn);  // mean(tn) = sum(qw) - means
    }
}

extern "C" void kernel_launch(void* const* d_in, const int* in_sizes, int n_in,
                              void* d_out, int out_size, void* d_ws, size_t ws_size,
                              hipStream_t stream) {
    const float* pred  = (const float*)d_in[0];
    const int*   truth = (const int*)d_in[1];
    const float* qw    = (const float*)d_in[2];
    float*  out      = (float*)d_out;
    float4* partials = (float4*)d_ws;   // 2048 * 16 B = 32 KiB scratch

    dim3 grid(QBLOCKS, BATCH);
    metric_main_kernel<<<grid, 256, 0, stream>>>(pred, truth, qw, partials);
    metric_final_kernel<<<1, 256, 0, stream>>>(partials, out);
}

// Round 4
// 91.631 us; speedup vs baseline: 4.5541x; 1.1677x over previous
//
#include <hip/hip_runtime.h>

#define NLAT 721
#define NLON 1440
#define NPIX (NLAT * NLON)   // 1,038,240 (divisible by 4)
#define NQ   (NPIX / 4)      // 259,560 quads per batch
#define BATCH 8
#define NCLS 16
#define IGNORE_IDX (-100)
#define QCHUNK 1024                       // contiguous quads per block
#define NBX ((NQ + QCHUNK - 1) / QCHUNK)  // 254 x-blocks per batch

typedef float vf4 __attribute__((ext_vector_type(4)));
typedef int   vi4 __attribute__((ext_vector_type(4)));

// Main pass: per-pixel argmax over 16 classes + weighted match/unmatch sums.
// Grid: (NBX, BATCH), 256 threads. Each block owns a CONTIGUOUS 1024-quad
// chunk (16 KB per class-stream) for DRAM page locality; pred/truth are
// loaded nontemporal (read-once, don't evict the reused qw from L2/L3).
__global__ __launch_bounds__(256) void metric_main_kernel(
    const float* __restrict__ pred,     // [B, C, NPIX]
    const int*   __restrict__ truth,    // [B, NPIX]
    const float* __restrict__ qw,       // [NPIX]
    float4*      __restrict__ partials) // [BATCH*NBX] {tp,fp,fn,qs}
{
    const int b = blockIdx.y;
    const float* pb = pred  + (size_t)b * NCLS * NPIX;
    const int*   tb = truth + (size_t)b * NPIX;
    const int qbase = blockIdx.x * QCHUNK;

    float tp = 0.f, fp = 0.f, fn = 0.f, qs = 0.f;

    #pragma unroll 1
    for (int it = 0; it < QCHUNK / 256; ++it) {
        const int q = qbase + it * 256 + threadIdx.x;
        if (q >= NQ) break;
        const int i = q * 4;

        // Burst: all 16 class loads issued before any use; asm pin keeps all
        // 16 float4s live so the compiler can't re-serialize them (R2 failure
        // mode: VGPR=36, latency-bound at 417us).
        vf4 v[NCLS];
        #pragma unroll
        for (int c = 0; c < NCLS; ++c)
            v[c] = __builtin_nontemporal_load(
                reinterpret_cast<const vf4*>(pb + (size_t)c * NPIX + i));
        asm volatile("" : "+v"(v[0]), "+v"(v[1]), "+v"(v[2]), "+v"(v[3]),
                          "+v"(v[4]), "+v"(v[5]), "+v"(v[6]), "+v"(v[7]),
                          "+v"(v[8]), "+v"(v[9]), "+v"(v[10]), "+v"(v[11]),
                          "+v"(v[12]), "+v"(v[13]), "+v"(v[14]), "+v"(v[15]));

        const vi4    t = __builtin_nontemporal_load(
                             reinterpret_cast<const vi4*>(tb + i));
        const float4 w = *reinterpret_cast<const float4*>(qw + i);

        // Branchless argmax; strict '>' keeps FIRST max (jnp.argmax tie rule).
        vf4 best = v[0];
        int bx = 0, by = 0, bz = 0, bw = 0;
        #pragma unroll
        for (int c = 1; c < NCLS; ++c) {
            bx = (v[c].x > best.x) ? c : bx;  best.x = fmaxf(best.x, v[c].x);
            by = (v[c].y > best.y) ? c : by;  best.y = fmaxf(best.y, v[c].y);
            bz = (v[c].z > best.z) ? c : bz;  best.z = fmaxf(best.z, v[c].z);
            bw = (v[c].w > best.w) ? c : bw;  best.w = fmaxf(best.w, v[c].w);
        }

        const int   oc[4] = {bx, by, bz, bw};
        const int   tt[4] = {t.x, t.y, t.z, t.w};
        const float ww[4] = {w.x, w.y, w.z, w.w};

        #pragma unroll
        for (int e = 0; e < 4; ++e) {
            const bool ign = (tt[e] == IGNORE_IDX);
            const int  tv  = ign ? -1 : tt[e];
            const int  ov  = ign ? -1 : oc[e];
            const bool matched = (tv == ov);
            const bool vt = (tv >= 0) && (tv < NCLS);
            const bool vo = (ov >= 0) && (ov < NCLS);
            const float wv = ww[e];
            tp += (matched  && vt) ? wv : 0.f;
            fn += (!matched && vt) ? wv : 0.f;
            fp += (!matched && vo) ? wv : 0.f;
        }
        if (b == 0) qs += ww[0] + ww[1] + ww[2] + ww[3];
    }

    // Wave64 reduce.
    #pragma unroll
    for (int off = 32; off > 0; off >>= 1) {
        tp += __shfl_down(tp, off);
        fp += __shfl_down(fp, off);
        fn += __shfl_down(fn, off);
        qs += __shfl_down(qs, off);
    }

    __shared__ float s[4][4];
    const int wid  = threadIdx.x >> 6;
    const int lane = threadIdx.x & 63;
    if (lane == 0) { s[wid][0] = tp; s[wid][1] = fp; s[wid][2] = fn; s[wid][3] = qs; }
    __syncthreads();

    if (threadIdx.x == 0) {
        float4 p = make_float4(0.f, 0.f, 0.f, 0.f);
        #pragma unroll
        for (int k = 0; k < 4; ++k) {
            p.x += s[k][0]; p.y += s[k][1]; p.z += s[k][2]; p.w += s[k][3];
        }
        partials[blockIdx.y * NBX + blockIdx.x] = p;  // plain store, no atomic
    }
}

// Reduce BATCH*NBX float4 partials -> 4 outputs (double at the end).
__global__ __launch_bounds__(256) void metric_final_kernel(
    const float4* __restrict__ partials, float* __restrict__ out)
{
    float a0 = 0.f, a1 = 0.f, a2 = 0.f, a3 = 0.f;
    for (int k = threadIdx.x; k < BATCH * NBX; k += 256) {
        const float4 p = partials[k];
        a0 += p.x; a1 += p.y; a2 += p.z; a3 += p.w;
    }
    #pragma unroll
    for (int off = 32; off > 0; off >>= 1) {
        a0 += __shfl_down(a0, off);
        a1 += __shfl_down(a1, off);
        a2 += __shfl_down(a2, off);
        a3 += __shfl_down(a3, off);
    }
    __shared__ float s[4][4];
    const int wid  = threadIdx.x >> 6;
    const int lane = threadIdx.x & 63;
    if (lane == 0) { s[wid][0] = a0; s[wid][1] = a1; s[wid][2] = a2; s[wid][3] = a3; }
    __syncthreads();

    if (threadIdx.x == 0) {
        double tp = 0.0, fp = 0.0, fn = 0.0, qs = 0.0;
        #pragma unroll
        for (int k = 0; k < 4; ++k) {
            tp += s[k][0]; fp += s[k][1]; fn += s[k][2]; qs += s[k][3];
        }
        const double inv = 1.0 / (double)(BATCH * NCLS);
        tp *= inv; fp *= inv; fn *= inv;
        out[0] = (float)tp;
        out[1] = (float)fp;
        out[2] = (float)fn;
        out[3] = (float)(qs - tp - fp - fn);  // mean(tn) = sum(qw) - means
    }
}

extern "C" void kernel_launch(void* const* d_in, const int* in_sizes, int n_in,
                              void* d_out, int out_size, void* d_ws, size_t ws_size,
                              hipStream_t stream) {
    const float* pred  = (const float*)d_in[0];
    const int*   truth = (const int*)d_in[1];
    const float* qw    = (const float*)d_in[2];
    float*  out      = (float*)d_out;
    float4* partials = (float4*)d_ws;   // BATCH*NBX*16 B = ~32 KiB scratch

    dim3 grid(NBX, BATCH);
    metric_main_kernel<<<grid, 256, 0, stream>>>(pred, truth, qw, partials);
    metric_final_kernel<<<1, 256, 0, stream>>>(partials, out);
}